// Round 12
// baseline (176.084 us; speedup 1.0000x reference)
//
#include <hip/hip_runtime.h>
#include <math.h>

typedef unsigned int uint;
typedef unsigned long ulong;
typedef unsigned char uchar;
typedef __attribute__((ext_vector_type(4))) float f32x4;
typedef uint __attribute__((may_alias)) uint_a;   // aliasing-safe LDS access

// Problem constants
#define BB  16384
#define DD  64
#define NT_ 128
#define NZ_ 2048
#define NJ_ 2049   // NZ+1

// workspace layout (float offsets)
#define BIAS_OFF 0         // fp32 [64]
#define CCS_OFF  64        // fp32 [2048]
#define INVS_OFF 2112      // fp32 [2048]
#define QS_OFF   4160      // fp32 [2048]
#define CZ8A_OFF 6208      // fp8 cz k0 [NZ][32]
#define CZ8B_OFF 22592     // fp8 cz k1 [NZ][32]
#define WZ8A_OFF 38976     // fp8 WzT k0 [NZ][32]
#define WZ8B_OFF 55360     // fp8 WzT k1 [NZ][32]
#define WZBP_OFF 71744     // fp8 Wz packed [64 chunks][64 d][32 c]
#define PART_OFF 104512    // fp32 partials [4][64][NJ_] = 524544
// end 629056 floats ~= 2.5 MB

// ---------------- fp8 e4m3 (OCP) conversion helpers ----------------
#if __has_builtin(__builtin_amdgcn_cvt_pk_fp8_f32)
__device__ __forceinline__ uint pk4_fp8(float a, float b, float c, float d) {
  int v = __builtin_amdgcn_cvt_pk_fp8_f32(a, b, 0, false);
  v = __builtin_amdgcn_cvt_pk_fp8_f32(c, d, v, true);
  return (uint)v;
}
__device__ __forceinline__ uchar f8_1(float x) {
  return (uchar)(__builtin_amdgcn_cvt_pk_fp8_f32(x, x, 0, false) & 0xFF);
}
#else
__device__ __forceinline__ uint sw_f8(float x) {
  uint u = __float_as_uint(x);
  uint s = (u >> 24) & 0x80u;
  float ax = __uint_as_float(u & 0x7FFFFFFFu);
  if (!(ax >= 0.015625f)) return s;          // flush tiny / NaN -> signed zero
  if (ax >= 448.f) return s | 0x7Eu;
  uint q = __float_as_uint(ax);
  q += 0x7FFFFu + ((q >> 20) & 1u);          // RNE at mantissa bit 20
  uint e = (q >> 23) - 120u;                 // rebias (127 -> 7)
  return s | ((e & 0xFu) << 3) | ((q >> 20) & 7u);
}
__device__ __forceinline__ uchar f8_1(float x) { return (uchar)sw_f8(x); }
__device__ __forceinline__ uint pk4_fp8(float a, float b, float c, float d) {
  return sw_f8(a) | (sw_f8(b) << 8) | (sw_f8(c) << 16) | (sw_f8(d) << 24);
}
#endif

// ---------------------------------------------------------------------------
// Kernel 1 (stage 1): split-K partial sums of W_t = einsum('dij,i->dj').
__global__ __launch_bounds__(256) void k_wt1(
    const float* __restrict__ t, const float* __restrict__ ct,
    const float* __restrict__ lst, const float* __restrict__ W,
    float* __restrict__ part)   // [4][64][NJ_]
{
  __shared__ float ph[32];
  int tx = threadIdx.x;
  int d  = blockIdx.y;
  int ic = blockIdx.z;
  if (tx < 32) {
    int i = ic * 32 + tx;
    float r = fabsf(t[0] - ct[i]) * __expf(-lst[i]);
    ph[tx] = __expf(-r * r);
  }
  __syncthreads();
  int j = blockIdx.x * 256 + tx;
  if (j >= NJ_) return;
  const float* Wp = W + (size_t)d * NT_ * NJ_ + (size_t)(ic * 32) * NJ_ + j;
  float acc = 0.f;
#pragma unroll
  for (int k = 0; k < 32; ++k) acc += Wp[(size_t)k * NJ_] * ph[k];
  part[((size_t)ic * 64 + d) * NJ_ + j] = acc;
}

// ---------------------------------------------------------------------------
// Kernel 2 (stage 2): 256 blocks x 256 thr, 8 centres/block.
// Reduce partials; emit fp8 tables + SoA scalars (ccs/invs/qs) + bias.
__global__ __launch_bounds__(256) void k_prep2(
    const float* __restrict__ part, const float* __restrict__ cz,
    const float* __restrict__ lsz,
    float* __restrict__ bias, float* __restrict__ ccs,
    float* __restrict__ invs, float* __restrict__ qs,
    uchar* __restrict__ cz8a, uchar* __restrict__ cz8b,
    uchar* __restrict__ wz8a, uchar* __restrict__ wz8b,
    uchar* __restrict__ wzbp8)
{
  __shared__ float wt[64][9];   // [d][c_local]
  int tid = threadIdx.x;
  int cb0 = blockIdx.x * 8;
#pragma unroll
  for (int h = 0; h < 2; ++h) {
    int f = h * 256 + tid;      // 512 = 64 d x 8 c
    int d = f >> 3, c = f & 7;
    size_t idx = (size_t)d * NJ_ + cb0 + c;
    float s = part[idx] + part[(size_t)64 * NJ_ + idx]
            + part[(size_t)128 * NJ_ + idx] + part[(size_t)192 * NJ_ + idx];
    wt[d][c] = s;
    int cg = cb0 + c;
    wzbp8[((size_t)(cg >> 5) * 64 + d) * 32 + (cg & 31)] = f8_1(s);
  }
  if (blockIdx.x == 0 && tid < 64) {
    size_t idx = (size_t)tid * NJ_ + 2048;
    bias[tid] = part[idx] + part[(size_t)64 * NJ_ + idx]
              + part[(size_t)128 * NJ_ + idx] + part[(size_t)192 * NJ_ + idx];
  }
  __syncthreads();
  int cl = tid >> 5;            // centre within block 0..7
  int k  = tid & 31;            // 0..31
  int c  = cb0 + cl;
  float cv0 = cz[(size_t)c * DD + k];
  float cv1 = cz[(size_t)c * DD + 32 + k];
  cz8a[(size_t)c * 32 + k] = f8_1(cv0);
  cz8b[(size_t)c * 32 + k] = f8_1(cv1);
  float w0 = wt[k][cl], w1 = wt[32 + k][cl];
  wz8a[(size_t)c * 32 + k] = f8_1(w0);
  wz8b[(size_t)c * 32 + k] = f8_1(w1);
  float ca = cv0 * cv0 + cv1 * cv1;
  float qa = w0 * cv0 + w1 * cv1;
  qa += __shfl_xor(qa, 1);  ca += __shfl_xor(ca, 1);
  qa += __shfl_xor(qa, 2);  ca += __shfl_xor(ca, 2);
  qa += __shfl_xor(qa, 4);  ca += __shfl_xor(ca, 4);
  qa += __shfl_xor(qa, 8);  ca += __shfl_xor(ca, 8);
  qa += __shfl_xor(qa, 16); ca += __shfl_xor(ca, 16);
  if (k == 0) {
    ccs[c]  = ca;
    invs[c] = __expf(-2.f * lsz[c]);
    qs[c]   = qa;
  }
}

// ---------------------------------------------------------------------------
// Main fused MFMA kernel — fp8, transposed GEMM1, pipelined, fully unrolled.
// Block: 256 thr = 4 waves = 4-way c-split; BM=32 (2 M-tiles/wave); grid 512.
// GEMM1 computes S^T = [cz|WzT] @ z^T so each lane holds 4 consecutive-c phi
// values for fixed m -> one pk4 + one b32 LDS store; GEMM2 A = 2 b32 LDS loads.
// ALL phi LDS accesses use uint_a (may_alias) so the compiler keeps ordering.
#define PH_LD 40   // bytes per phi m-row (32 + 8 pad); /4 = 10 uints

__global__ __launch_bounds__(256) void k_fused(
    const float* __restrict__ z,     // [BB][64] fp32
    const uchar* __restrict__ cz8a, const uchar* __restrict__ cz8b,
    const uchar* __restrict__ wz8a, const uchar* __restrict__ wz8b,
    const uchar* __restrict__ wzbp8,
    const float* __restrict__ ccs, const float* __restrict__ invs,
    const float* __restrict__ qs, const float* __restrict__ bias,
    float* __restrict__ out)
{
  // phi [2 parity][4 wave][2 mt][16 m][PH_LD]  (10240 B)  OR  eps [32][68] f32
  __shared__ char smem[10240];
  __shared__ float dlr[4][32];
  uchar* phs = (uchar*)smem;
  float* eps = (float*)smem;

  int tid  = threadIdx.x;
  int ws   = tid >> 6;           // wave = c-split group 0..3
  int lane = tid & 63;
  int lrow = lane & 15, quad = lane >> 4;
  int b0 = blockIdx.x * 32;

  // z fragments (B operand) from fp32 z, packed to fp8 in-register; exact zz.
  long az[2][2];
  float zzs[2];                  // zz[m = mt*16 + lrow]
#pragma unroll
  for (int mt = 0; mt < 2; ++mt) {
    const float* zr = z + (size_t)(b0 + mt * 16 + lrow) * DD;
    float4 u0 = *(const float4*)(zr + quad * 8);
    float4 u1 = *(const float4*)(zr + quad * 8 + 4);
    float4 u2 = *(const float4*)(zr + 32 + quad * 8);
    float4 u3 = *(const float4*)(zr + 32 + quad * 8 + 4);
    uint l0 = pk4_fp8(u0.x, u0.y, u0.z, u0.w);
    uint h0 = pk4_fp8(u1.x, u1.y, u1.z, u1.w);
    uint l1 = pk4_fp8(u2.x, u2.y, u2.z, u2.w);
    uint h1 = pk4_fp8(u3.x, u3.y, u3.z, u3.w);
    az[mt][0] = (long)((ulong)l0 | ((ulong)h0 << 32));
    az[mt][1] = (long)((ulong)l1 | ((ulong)h1 << 32));
    float p = u0.x*u0.x + u0.y*u0.y + u0.z*u0.z + u0.w*u0.w
            + u1.x*u1.x + u1.y*u1.y + u1.z*u1.z + u1.w*u1.w
            + u2.x*u2.x + u2.y*u2.y + u2.z*u2.z + u2.w*u2.w
            + u3.x*u3.x + u3.y*u3.y + u3.z*u3.z + u3.w*u3.w;
    p += __shfl_xor(p, 16);
    p += __shfl_xor(p, 32);      // all quads now hold zz[row mt*16+lrow]
    zzs[mt] = p;
  }

  f32x4 acc[2][4];               // acc[mt][nt]: D[m=quad*4+i][d=nt*16+lrow]
#pragma unroll
  for (int mt = 0; mt < 2; ++mt)
#pragma unroll
    for (int nt = 0; nt < 4; ++nt) acc[mt][nt] = (f32x4){0.f, 0.f, 0.f, 0.f};
  float dl[2] = {0.f, 0.f};

  const f32x4 zero = (f32x4){0.f, 0.f, 0.f, 0.f};
  int cbase = ws * 512;
  int pwave = ws * 2 * 16 * PH_LD;   // per-wave phi region within a parity bank

  // ---- register double-buffered prefetch state (tables only) ----
  long Abc0[2][2], Abc1[2][2], Abw0[2][2], Abw1[2][2], Abb[2][4];
#define LOADB(PAR, C0)                                                         \
  do {                                                                         \
    int c0_ = (C0);                                                            \
    _Pragma("unroll")                                                          \
    for (int nt = 0; nt < 2; ++nt) {                                           \
      int cg_ = c0_ + nt * 16 + lrow;                                          \
      size_t ro_ = (size_t)cg_ * 32 + quad * 8;                                \
      Abc0[PAR][nt] = *(const long*)(cz8a + ro_);                              \
      Abc1[PAR][nt] = *(const long*)(cz8b + ro_);                              \
      Abw0[PAR][nt] = *(const long*)(wz8a + ro_);                              \
      Abw1[PAR][nt] = *(const long*)(wz8b + ro_);                              \
    }                                                                          \
    size_t cb_ = (size_t)(c0_ >> 5) * 64 * 32;                                 \
    _Pragma("unroll")                                                          \
    for (int nt = 0; nt < 4; ++nt)                                             \
      Abb[PAR][nt] =                                                           \
          *(const long*)(wzbp8 + cb_ + (size_t)(nt * 16 + lrow) * 32 + quad * 8); \
  } while (0)

  LOADB(0, cbase);
#pragma unroll
  for (int it = 0; it < 16; ++it) {
    const int par = it & 1;
    const int c0 = cbase + it * 32;
    // prefetch next chunk (last iter re-fetches chunk 0: compile-time, in-bounds)
    LOADB(par ^ 1, (it == 15) ? cbase : (c0 + 32));

    const int pb = par * 5120 + pwave;
    // ---- GEMM1 (transposed) + elementwise ----
#pragma unroll
    for (int nt = 0; nt < 2; ++nt) {
      int cs = c0 + nt * 16 + quad * 4;        // this lane's 4 consecutive c
      f32x4 cc4 = *(const f32x4*)(ccs + cs);
      f32x4 iv4 = *(const f32x4*)(invs + cs);
      f32x4 q4  = *(const f32x4*)(qs + cs);
#pragma unroll
      for (int mt = 0; mt < 2; ++mt) {
        f32x4 d1 = __builtin_amdgcn_mfma_f32_16x16x32_fp8_fp8(Abc0[par][nt], az[mt][0], zero, 0, 0, 0);
        d1       = __builtin_amdgcn_mfma_f32_16x16x32_fp8_fp8(Abc1[par][nt], az[mt][1], d1,   0, 0, 0);
        f32x4 d2 = __builtin_amdgcn_mfma_f32_16x16x32_fp8_fp8(Abw0[par][nt], az[mt][0], zero, 0, 0, 0);
        d2       = __builtin_amdgcn_mfma_f32_16x16x32_fp8_fp8(Abw1[par][nt], az[mt][1], d2,   0, 0, 0);
        float zz = zzs[mt];
        float s0 = fmaxf(fmaf(-2.f, d1[0], zz + cc4[0]), 0.f);
        float s1 = fmaxf(fmaf(-2.f, d1[1], zz + cc4[1]), 0.f);
        float s2 = fmaxf(fmaf(-2.f, d1[2], zz + cc4[2]), 0.f);
        float s3 = fmaxf(fmaf(-2.f, d1[3], zz + cc4[3]), 0.f);
        float p0 = __expf(-s0 * iv4[0]);
        float p1 = __expf(-s1 * iv4[1]);
        float p2 = __expf(-s2 * iv4[2]);
        float p3 = __expf(-s3 * iv4[3]);
        dl[mt] += p0 * iv4[0] * (d2[0] - q4[0])
                + p1 * iv4[1] * (d2[1] - q4[1])
                + p2 * iv4[2] * (d2[2] - q4[2])
                + p3 * iv4[3] * (d2[3] - q4[3]);
        // one packed b32 store: phi[m=lrow][c_local = nt*16+quad*4 .. +4]
        uint_a* pw = (uint_a*)(phs + pb + (mt * 16 + lrow) * PH_LD);
        pw[nt * 4 + quad] = pk4_fp8(p0, p1, p2, p3);
      }
    }
    // ---- GEMM2: dz[m][d] += phi[m][c] * Wz[d][c] ----
#pragma unroll
    for (int mt = 0; mt < 2; ++mt) {
      const uint_a* pr = (const uint_a*)(phs + pb + (mt * 16 + lrow) * PH_LD);
      uint plo = pr[quad * 2];
      uint phi_ = pr[quad * 2 + 1];
      long ap = (long)((ulong)plo | ((ulong)phi_ << 32));
#pragma unroll
      for (int nt = 0; nt < 4; ++nt)
        acc[mt][nt] = __builtin_amdgcn_mfma_f32_16x16x32_fp8_fp8(ap, Abb[par][nt], acc[mt][nt], 0, 0, 0);
    }
  }
#undef LOADB

  // ---- dl: reduce across quads (c-slices), write per (wave, m) ----
#pragma unroll
  for (int mt = 0; mt < 2; ++mt) {
    float v = dl[mt];
    v += __shfl_xor(v, 16);
    v += __shfl_xor(v, 32);
    if (quad == 0) dlr[ws][mt * 16 + lrow] = v;
  }

  // ---- dz combine across the 4 c-split waves (eps reuses phi LDS) ----
  for (int s = 0; s < 4; ++s) {
    __syncthreads();
    if (ws == s) {
#pragma unroll
      for (int mt = 0; mt < 2; ++mt)
#pragma unroll
        for (int nt = 0; nt < 4; ++nt)
#pragma unroll
          for (int i = 0; i < 4; ++i) {
            int r = mt * 16 + quad * 4 + i;
            int d = nt * 16 + lrow;
            if (s == 0) eps[r * 68 + d] = acc[mt][nt][i];
            else        eps[r * 68 + d] += acc[mt][nt][i];
          }
    }
  }
  __syncthreads();

  // ---- outputs ----
  {
    int r = tid >> 3, d0 = (tid & 7) * 8;   // 256 thr x 8 floats = 32x64
    float4 e0 = *(const float4*)&eps[r * 68 + d0];
    float4 e1 = *(const float4*)&eps[r * 68 + d0 + 4];
    float4 bv0 = *(const float4*)&bias[d0];
    float4 bv1 = *(const float4*)&bias[d0 + 4];
    float4 o0, o1;
    o0.x = e0.x + bv0.x; o0.y = e0.y + bv0.y; o0.z = e0.z + bv0.z; o0.w = e0.w + bv0.w;
    o1.x = e1.x + bv1.x; o1.y = e1.y + bv1.y; o1.z = e1.z + bv1.z; o1.w = e1.w + bv1.w;
    *(float4*)&out[(size_t)(b0 + r) * DD + d0]     = o0;
    *(float4*)&out[(size_t)(b0 + r) * DD + d0 + 4] = o1;
  }
  if (tid < 32) {
    float s = dlr[0][tid] + dlr[1][tid] + dlr[2][tid] + dlr[3][tid];
    out[(size_t)BB * DD + b0 + tid] = 2.f * s;
  }
}

// ---------------------------------------------------------------------------
extern "C" void kernel_launch(void* const* d_in, const int* in_sizes, int n_in,
                              void* d_out, int out_size, void* d_ws, size_t ws_size,
                              hipStream_t stream)
{
  const float* t   = (const float*)d_in[0];
  const float* z   = (const float*)d_in[1];
  // d_in[2] = logp_z (unused)
  const float* cz  = (const float*)d_in[3];
  const float* lsz = (const float*)d_in[4];
  const float* ct  = (const float*)d_in[5];
  const float* lst = (const float*)d_in[6];
  const float* W   = (const float*)d_in[7];
  float* out = (float*)d_out;
  float* ws  = (float*)d_ws;

  float*  bias = ws + BIAS_OFF;
  float*  ccs  = ws + CCS_OFF;
  float*  invs = ws + INVS_OFF;
  float*  qs   = ws + QS_OFF;
  uchar*  cz8a = (uchar*)(ws + CZ8A_OFF);
  uchar*  cz8b = (uchar*)(ws + CZ8B_OFF);
  uchar*  wz8a = (uchar*)(ws + WZ8A_OFF);
  uchar*  wz8b = (uchar*)(ws + WZ8B_OFF);
  uchar*  wzbp8 = (uchar*)(ws + WZBP_OFF);
  float*  part = ws + PART_OFF;

  k_wt1<<<dim3(9, 64, 4), 256, 0, stream>>>(t, ct, lst, W, part);
  k_prep2<<<dim3(256), 256, 0, stream>>>(part, cz, lsz, bias, ccs, invs, qs,
                                         cz8a, cz8b, wz8a, wz8b, wzbp8);
  k_fused<<<dim3(BB / 32), 256, 0, stream>>>(z, cz8a, cz8b, wz8a, wz8b,
                                             wzbp8, ccs, invs, qs, bias, out);
}

// Round 13
// 148.237 us; speedup vs baseline: 1.1879x; 1.1879x over previous
//
#include <hip/hip_runtime.h>
#include <math.h>

typedef unsigned int uint;
typedef unsigned long ulong;
typedef unsigned char uchar;
typedef __attribute__((ext_vector_type(4))) float f32x4;
typedef uint __attribute__((may_alias)) uint_a;   // aliasing-safe LDS access

// Problem constants
#define BB  16384
#define DD  64
#define NT_ 128
#define NZ_ 2048
#define NJ_ 2049   // NZ+1

// workspace layout (float offsets)
#define BIAS_OFF 0         // fp32 [64]
#define CCS_OFF  64        // fp32 [2048]
#define INVS_OFF 2112      // fp32 [2048]
#define QS_OFF   4160      // fp32 [2048]
#define CZ8A_OFF 6208      // fp8 cz k0 [NZ][32]
#define CZ8B_OFF 22592     // fp8 cz k1 [NZ][32]
#define WZ8A_OFF 38976     // fp8 WzT k0 [NZ][32]
#define WZ8B_OFF 55360     // fp8 WzT k1 [NZ][32]
#define WZBP_OFF 71744     // fp8 Wz packed [64 chunks][64 d][32 c]
#define PART_OFF 104512    // fp32 partials [4][64][NJ_] = 524544
// end 629056 floats ~= 2.5 MB

// ---------------- fp8 e4m3 (OCP) conversion helpers ----------------
#if __has_builtin(__builtin_amdgcn_cvt_pk_fp8_f32)
__device__ __forceinline__ uint pk4_fp8(float a, float b, float c, float d) {
  int v = __builtin_amdgcn_cvt_pk_fp8_f32(a, b, 0, false);
  v = __builtin_amdgcn_cvt_pk_fp8_f32(c, d, v, true);
  return (uint)v;
}
__device__ __forceinline__ uchar f8_1(float x) {
  return (uchar)(__builtin_amdgcn_cvt_pk_fp8_f32(x, x, 0, false) & 0xFF);
}
#else
__device__ __forceinline__ uint sw_f8(float x) {
  uint u = __float_as_uint(x);
  uint s = (u >> 24) & 0x80u;
  float ax = __uint_as_float(u & 0x7FFFFFFFu);
  if (!(ax >= 0.015625f)) return s;          // flush tiny / NaN -> signed zero
  if (ax >= 448.f) return s | 0x7Eu;
  uint q = __float_as_uint(ax);
  q += 0x7FFFFu + ((q >> 20) & 1u);          // RNE at mantissa bit 20
  uint e = (q >> 23) - 120u;                 // rebias (127 -> 7)
  return s | ((e & 0xFu) << 3) | ((q >> 20) & 7u);
}
__device__ __forceinline__ uchar f8_1(float x) { return (uchar)sw_f8(x); }
__device__ __forceinline__ uint pk4_fp8(float a, float b, float c, float d) {
  return sw_f8(a) | (sw_f8(b) << 8) | (sw_f8(c) << 16) | (sw_f8(d) << 24);
}
#endif

// ---------------------------------------------------------------------------
// Kernel 1 (stage 1): split-K partial sums of W_t = einsum('dij,i->dj').
__global__ __launch_bounds__(256) void k_wt1(
    const float* __restrict__ t, const float* __restrict__ ct,
    const float* __restrict__ lst, const float* __restrict__ W,
    float* __restrict__ part)   // [4][64][NJ_]
{
  __shared__ float ph[32];
  int tx = threadIdx.x;
  int d  = blockIdx.y;
  int ic = blockIdx.z;
  if (tx < 32) {
    int i = ic * 32 + tx;
    float r = fabsf(t[0] - ct[i]) * __expf(-lst[i]);
    ph[tx] = __expf(-r * r);
  }
  __syncthreads();
  int j = blockIdx.x * 256 + tx;
  if (j >= NJ_) return;
  const float* Wp = W + (size_t)d * NT_ * NJ_ + (size_t)(ic * 32) * NJ_ + j;
  float acc = 0.f;
#pragma unroll
  for (int k = 0; k < 32; ++k) acc += Wp[(size_t)k * NJ_] * ph[k];
  part[((size_t)ic * 64 + d) * NJ_ + j] = acc;
}

// ---------------------------------------------------------------------------
// Kernel 2 (stage 2): 256 blocks x 256 thr, 8 centres/block.
// Reduce partials; emit fp8 tables + SoA scalars (ccs/invs/qs) + bias.
__global__ __launch_bounds__(256) void k_prep2(
    const float* __restrict__ part, const float* __restrict__ cz,
    const float* __restrict__ lsz,
    float* __restrict__ bias, float* __restrict__ ccs,
    float* __restrict__ invs, float* __restrict__ qs,
    uchar* __restrict__ cz8a, uchar* __restrict__ cz8b,
    uchar* __restrict__ wz8a, uchar* __restrict__ wz8b,
    uchar* __restrict__ wzbp8)
{
  __shared__ float wt[64][9];   // [d][c_local]
  int tid = threadIdx.x;
  int cb0 = blockIdx.x * 8;
#pragma unroll
  for (int h = 0; h < 2; ++h) {
    int f = h * 256 + tid;      // 512 = 64 d x 8 c
    int d = f >> 3, c = f & 7;
    size_t idx = (size_t)d * NJ_ + cb0 + c;
    float s = part[idx] + part[(size_t)64 * NJ_ + idx]
            + part[(size_t)128 * NJ_ + idx] + part[(size_t)192 * NJ_ + idx];
    wt[d][c] = s;
    int cg = cb0 + c;
    wzbp8[((size_t)(cg >> 5) * 64 + d) * 32 + (cg & 31)] = f8_1(s);
  }
  if (blockIdx.x == 0 && tid < 64) {
    size_t idx = (size_t)tid * NJ_ + 2048;
    bias[tid] = part[idx] + part[(size_t)64 * NJ_ + idx]
              + part[(size_t)128 * NJ_ + idx] + part[(size_t)192 * NJ_ + idx];
  }
  __syncthreads();
  int cl = tid >> 5;            // centre within block 0..7
  int k  = tid & 31;            // 0..31
  int c  = cb0 + cl;
  float cv0 = cz[(size_t)c * DD + k];
  float cv1 = cz[(size_t)c * DD + 32 + k];
  cz8a[(size_t)c * 32 + k] = f8_1(cv0);
  cz8b[(size_t)c * 32 + k] = f8_1(cv1);
  float w0 = wt[k][cl], w1 = wt[32 + k][cl];
  wz8a[(size_t)c * 32 + k] = f8_1(w0);
  wz8b[(size_t)c * 32 + k] = f8_1(w1);
  float ca = cv0 * cv0 + cv1 * cv1;
  float qa = w0 * cv0 + w1 * cv1;
  qa += __shfl_xor(qa, 1);  ca += __shfl_xor(ca, 1);
  qa += __shfl_xor(qa, 2);  ca += __shfl_xor(ca, 2);
  qa += __shfl_xor(qa, 4);  ca += __shfl_xor(ca, 4);
  qa += __shfl_xor(qa, 8);  ca += __shfl_xor(ca, 8);
  qa += __shfl_xor(qa, 16); ca += __shfl_xor(ca, 16);
  if (k == 0) {
    ccs[c]  = ca;
    invs[c] = __expf(-2.f * lsz[c]);
    qs[c]   = qa;
  }
}

// ---------------------------------------------------------------------------
// Main fused MFMA kernel — fp8, transposed GEMM1, pipelined (unroll 2).
// Block: 256 thr = 4 waves = 4-way c-split; BM=32 (2 M-tiles/wave); grid 512.
// GEMM1 computes S^T = [cz|WzT] @ z^T so each lane holds 4 consecutive-c phi
// values for fixed m -> one pk4 + one b32 LDS store; GEMM2 A = 2 b32 LDS loads.
// ALL phi LDS accesses use uint_a (may_alias) so the compiler keeps ordering.
#define PH_LD 40   // bytes per phi m-row (32 + 8 pad); /4 = 10 uints

__global__ __launch_bounds__(256) void k_fused(
    const float* __restrict__ z,     // [BB][64] fp32
    const uchar* __restrict__ cz8a, const uchar* __restrict__ cz8b,
    const uchar* __restrict__ wz8a, const uchar* __restrict__ wz8b,
    const uchar* __restrict__ wzbp8,
    const float* __restrict__ ccs, const float* __restrict__ invs,
    const float* __restrict__ qs, const float* __restrict__ bias,
    float* __restrict__ out)
{
  // phi [2 parity][4 wave][2 mt][16 m][PH_LD]  (10240 B)  OR  eps [32][68] f32
  __shared__ char smem[10240];
  __shared__ float dlr[4][32];
  uchar* phs = (uchar*)smem;
  float* eps = (float*)smem;

  int tid  = threadIdx.x;
  int ws   = tid >> 6;           // wave = c-split group 0..3
  int lane = tid & 63;
  int lrow = lane & 15, quad = lane >> 4;
  int b0 = blockIdx.x * 32;

  // z fragments (B operand) from fp32 z, packed to fp8 in-register; exact zz.
  long az[2][2];
  float zzs[2];                  // zz[m = mt*16 + lrow]
#pragma unroll
  for (int mt = 0; mt < 2; ++mt) {
    const float* zr = z + (size_t)(b0 + mt * 16 + lrow) * DD;
    float4 u0 = *(const float4*)(zr + quad * 8);
    float4 u1 = *(const float4*)(zr + quad * 8 + 4);
    float4 u2 = *(const float4*)(zr + 32 + quad * 8);
    float4 u3 = *(const float4*)(zr + 32 + quad * 8 + 4);
    uint l0 = pk4_fp8(u0.x, u0.y, u0.z, u0.w);
    uint h0 = pk4_fp8(u1.x, u1.y, u1.z, u1.w);
    uint l1 = pk4_fp8(u2.x, u2.y, u2.z, u2.w);
    uint h1 = pk4_fp8(u3.x, u3.y, u3.z, u3.w);
    az[mt][0] = (long)((ulong)l0 | ((ulong)h0 << 32));
    az[mt][1] = (long)((ulong)l1 | ((ulong)h1 << 32));
    float p = u0.x*u0.x + u0.y*u0.y + u0.z*u0.z + u0.w*u0.w
            + u1.x*u1.x + u1.y*u1.y + u1.z*u1.z + u1.w*u1.w
            + u2.x*u2.x + u2.y*u2.y + u2.z*u2.z + u2.w*u2.w
            + u3.x*u3.x + u3.y*u3.y + u3.z*u3.z + u3.w*u3.w;
    p += __shfl_xor(p, 16);
    p += __shfl_xor(p, 32);      // all quads now hold zz[row mt*16+lrow]
    zzs[mt] = p;
  }

  f32x4 acc[2][4];               // acc[mt][nt]: D[m=quad*4+i][d=nt*16+lrow]
#pragma unroll
  for (int mt = 0; mt < 2; ++mt)
#pragma unroll
    for (int nt = 0; nt < 4; ++nt) acc[mt][nt] = (f32x4){0.f, 0.f, 0.f, 0.f};
  float dl[2] = {0.f, 0.f};

  const f32x4 zero = (f32x4){0.f, 0.f, 0.f, 0.f};
  int cbase = ws * 512;
  int pwave = ws * 2 * 16 * PH_LD;   // per-wave phi region within a parity bank

  // ---- register double-buffered prefetch state (tables only) ----
  long Abc0[2][2], Abc1[2][2], Abw0[2][2], Abw1[2][2], Abb[2][4];
#define LOADB(PAR, C0)                                                         \
  do {                                                                         \
    int c0_ = (C0);                                                            \
    _Pragma("unroll")                                                          \
    for (int nt = 0; nt < 2; ++nt) {                                           \
      int cg_ = c0_ + nt * 16 + lrow;                                          \
      size_t ro_ = (size_t)cg_ * 32 + quad * 8;                                \
      Abc0[PAR][nt] = *(const long*)(cz8a + ro_);                              \
      Abc1[PAR][nt] = *(const long*)(cz8b + ro_);                              \
      Abw0[PAR][nt] = *(const long*)(wz8a + ro_);                              \
      Abw1[PAR][nt] = *(const long*)(wz8b + ro_);                              \
    }                                                                          \
    size_t cb_ = (size_t)(c0_ >> 5) * 64 * 32;                                 \
    _Pragma("unroll")                                                          \
    for (int nt = 0; nt < 4; ++nt)                                             \
      Abb[PAR][nt] =                                                           \
          *(const long*)(wzbp8 + cb_ + (size_t)(nt * 16 + lrow) * 32 + quad * 8); \
  } while (0)

  LOADB(0, cbase);
#pragma unroll 2
  for (int it = 0; it < 16; ++it) {
    int par = it & 1;
    int c0 = cbase + it * 32;
    // prefetch next chunk (wraps on last iter -> always in-bounds)
    LOADB(par ^ 1, cbase + ((it + 1) & 15) * 32);

    int pb = par * 5120 + pwave;
    // ---- GEMM1 (transposed) + elementwise ----
#pragma unroll
    for (int nt = 0; nt < 2; ++nt) {
      int cs = c0 + nt * 16 + quad * 4;        // this lane's 4 consecutive c
      f32x4 cc4 = *(const f32x4*)(ccs + cs);
      f32x4 iv4 = *(const f32x4*)(invs + cs);
      f32x4 q4  = *(const f32x4*)(qs + cs);
#pragma unroll
      for (int mt = 0; mt < 2; ++mt) {
        f32x4 d1 = __builtin_amdgcn_mfma_f32_16x16x32_fp8_fp8(Abc0[par][nt], az[mt][0], zero, 0, 0, 0);
        d1       = __builtin_amdgcn_mfma_f32_16x16x32_fp8_fp8(Abc1[par][nt], az[mt][1], d1,   0, 0, 0);
        f32x4 d2 = __builtin_amdgcn_mfma_f32_16x16x32_fp8_fp8(Abw0[par][nt], az[mt][0], zero, 0, 0, 0);
        d2       = __builtin_amdgcn_mfma_f32_16x16x32_fp8_fp8(Abw1[par][nt], az[mt][1], d2,   0, 0, 0);
        float zz = zzs[mt];
        float s0 = fmaxf(fmaf(-2.f, d1[0], zz + cc4[0]), 0.f);
        float s1 = fmaxf(fmaf(-2.f, d1[1], zz + cc4[1]), 0.f);
        float s2 = fmaxf(fmaf(-2.f, d1[2], zz + cc4[2]), 0.f);
        float s3 = fmaxf(fmaf(-2.f, d1[3], zz + cc4[3]), 0.f);
        float p0 = __expf(-s0 * iv4[0]);
        float p1 = __expf(-s1 * iv4[1]);
        float p2 = __expf(-s2 * iv4[2]);
        float p3 = __expf(-s3 * iv4[3]);
        dl[mt] += p0 * iv4[0] * (d2[0] - q4[0])
                + p1 * iv4[1] * (d2[1] - q4[1])
                + p2 * iv4[2] * (d2[2] - q4[2])
                + p3 * iv4[3] * (d2[3] - q4[3]);
        // one packed b32 store: phi[m=lrow][c_local = nt*16+quad*4 .. +4]
        uint_a* pw = (uint_a*)(phs + pb + (mt * 16 + lrow) * PH_LD);
        pw[nt * 4 + quad] = pk4_fp8(p0, p1, p2, p3);
      }
    }
    // ---- GEMM2: dz[m][d] += phi[m][c] * Wz[d][c] ----
#pragma unroll
    for (int mt = 0; mt < 2; ++mt) {
      const uint_a* pr = (const uint_a*)(phs + pb + (mt * 16 + lrow) * PH_LD);
      uint plo = pr[quad * 2];
      uint phi_ = pr[quad * 2 + 1];
      long ap = (long)((ulong)plo | ((ulong)phi_ << 32));
#pragma unroll
      for (int nt = 0; nt < 4; ++nt)
        acc[mt][nt] = __builtin_amdgcn_mfma_f32_16x16x32_fp8_fp8(ap, Abb[par][nt], acc[mt][nt], 0, 0, 0);
    }
  }
#undef LOADB

  // ---- dl: reduce across quads (c-slices), write per (wave, m) ----
#pragma unroll
  for (int mt = 0; mt < 2; ++mt) {
    float v = dl[mt];
    v += __shfl_xor(v, 16);
    v += __shfl_xor(v, 32);
    if (quad == 0) dlr[ws][mt * 16 + lrow] = v;
  }

  // ---- dz combine across the 4 c-split waves (eps reuses phi LDS) ----
  for (int s = 0; s < 4; ++s) {
    __syncthreads();
    if (ws == s) {
#pragma unroll
      for (int mt = 0; mt < 2; ++mt)
#pragma unroll
        for (int nt = 0; nt < 4; ++nt)
#pragma unroll
          for (int i = 0; i < 4; ++i) {
            int r = mt * 16 + quad * 4 + i;
            int d = nt * 16 + lrow;
            if (s == 0) eps[r * 68 + d] = acc[mt][nt][i];
            else        eps[r * 68 + d] += acc[mt][nt][i];
          }
    }
  }
  __syncthreads();

  // ---- outputs ----
  {
    int r = tid >> 3, d0 = (tid & 7) * 8;   // 256 thr x 8 floats = 32x64
    float4 e0 = *(const float4*)&eps[r * 68 + d0];
    float4 e1 = *(const float4*)&eps[r * 68 + d0 + 4];
    float4 bv0 = *(const float4*)&bias[d0];
    float4 bv1 = *(const float4*)&bias[d0 + 4];
    float4 o0, o1;
    o0.x = e0.x + bv0.x; o0.y = e0.y + bv0.y; o0.z = e0.z + bv0.z; o0.w = e0.w + bv0.w;
    o1.x = e1.x + bv1.x; o1.y = e1.y + bv1.y; o1.z = e1.z + bv1.z; o1.w = e1.w + bv1.w;
    *(float4*)&out[(size_t)(b0 + r) * DD + d0]     = o0;
    *(float4*)&out[(size_t)(b0 + r) * DD + d0 + 4] = o1;
  }
  if (tid < 32) {
    float s = dlr[0][tid] + dlr[1][tid] + dlr[2][tid] + dlr[3][tid];
    out[(size_t)BB * DD + b0 + tid] = 2.f * s;
  }
}

// ---------------------------------------------------------------------------
extern "C" void kernel_launch(void* const* d_in, const int* in_sizes, int n_in,
                              void* d_out, int out_size, void* d_ws, size_t ws_size,
                              hipStream_t stream)
{
  const float* t   = (const float*)d_in[0];
  const float* z   = (const float*)d_in[1];
  // d_in[2] = logp_z (unused)
  const float* cz  = (const float*)d_in[3];
  const float* lsz = (const float*)d_in[4];
  const float* ct  = (const float*)d_in[5];
  const float* lst = (const float*)d_in[6];
  const float* W   = (const float*)d_in[7];
  float* out = (float*)d_out;
  float* ws  = (float*)d_ws;

  float*  bias = ws + BIAS_OFF;
  float*  ccs  = ws + CCS_OFF;
  float*  invs = ws + INVS_OFF;
  float*  qs   = ws + QS_OFF;
  uchar*  cz8a = (uchar*)(ws + CZ8A_OFF);
  uchar*  cz8b = (uchar*)(ws + CZ8B_OFF);
  uchar*  wz8a = (uchar*)(ws + WZ8A_OFF);
  uchar*  wz8b = (uchar*)(ws + WZ8B_OFF);
  uchar*  wzbp8 = (uchar*)(ws + WZBP_OFF);
  float*  part = ws + PART_OFF;

  k_wt1<<<dim3(9, 64, 4), 256, 0, stream>>>(t, ct, lst, W, part);
  k_prep2<<<dim3(256), 256, 0, stream>>>(part, cz, lsz, bias, ccs, invs, qs,
                                         cz8a, cz8b, wz8a, wz8b, wzbp8);
  k_fused<<<dim3(BB / 32), 256, 0, stream>>>(z, cz8a, cz8b, wz8a, wz8b,
                                             wzbp8, ccs, invs, qs, bias, out);
}